// Round 3
// baseline (273.830 us; speedup 1.0000x reference)
//
#include <hip/hip_runtime.h>

#define B_ 4
#define S_ 2048
#define N_ 2048
#define H_ 16
#define D_ 1024

typedef short s4v __attribute__((ext_vector_type(4)));
typedef short s8v __attribute__((ext_vector_type(8)));
typedef float f4v __attribute__((ext_vector_type(4)));

__device__ __forceinline__ float bf2f(short s) {
  unsigned u = ((unsigned)(unsigned short)s) << 16;
  float f; __builtin_memcpy(&f, &u, 4); return f;
}
__device__ __forceinline__ short f2bf(float f) {
  unsigned u; __builtin_memcpy(&u, &f, 4);
  u += 0x7fffu + ((u >> 16) & 1u);
  return (short)(u >> 16);
}
__device__ __forceinline__ unsigned pack2bf(float a, float b) {
  unsigned ua, ub;
  __builtin_memcpy(&ua, &a, 4);
  __builtin_memcpy(&ub, &b, 4);
  return __builtin_amdgcn_perm(ub + 0x8000u, ua + 0x8000u, 0x07060302u);
}

// dtype-adaptive loads: F32=true -> buffer holds f32; else bf16
template<bool F32>
__device__ __forceinline__ float load1(const void* p, size_t i) {
  if constexpr (F32) return ((const float*)p)[i];
  else return bf2f(((const short*)p)[i]);
}
template<bool F32>
__device__ __forceinline__ s8v load8bf(const void* p, size_t i) {
  if constexpr (F32) {
    const f4v* q = (const f4v*)((const float*)p + i);
    f4v a = q[0], b = q[1];
    union { s8v v; unsigned u[4]; } o;
    o.u[0] = pack2bf(a[0], a[1]); o.u[1] = pack2bf(a[2], a[3]);
    o.u[2] = pack2bf(b[0], b[1]); o.u[3] = pack2bf(b[2], b[3]);
    return o.v;
  } else {
    return *(const s8v*)((const short*)p + i);
  }
}

// ---- runtime dtype detection: low-short exponent field of sampled dwords ----
// bf16 data: low short IS a bf16 ~N(0,1) -> exp in [110,129] -> ~64/64 votes.
// f32 data: low 16 bits are random mantissa bits -> ~10/64 votes.
__global__ void detect_dtype(const unsigned* xq, int* flag) {
  int t = threadIdx.x;  // 64 threads
  unsigned w = xq[(size_t)t * 65536 + 3];  // max idx < 4.19M dwords (bf16 case)
  unsigned e = (w >> 7) & 0xFFu;
  bool isbf = (e >= 100u && e <= 140u);
  unsigned long long ball = __ballot(isbf);
  if (t == 0) *flag = (__popcll(ball) >= 32) ? 1 : 0;  // 1 = bf16
}

// ---------------- LN over rows of 64 (K-norm) ----------------
template<bool F32>
__global__ __launch_bounds__(256) void rownorm64(
    const void* __restrict__ x, const void* __restrict__ w,
    const void* __restrict__ b, short* __restrict__ out,
    int nrows, const int* __restrict__ flag) {
  if ((*flag != 0) == F32) return;
  int gid = blockIdx.x * 256 + threadIdx.x;
  int row = gid >> 6, lane = gid & 63;
  if (row >= nrows) return;
  float v = load1<F32>(x, (size_t)row * 64 + lane);
  float s = v;
  #pragma unroll
  for (int mm = 1; mm < 64; mm <<= 1) s += __shfl_xor(s, mm, 64);
  float mean = s * 0.015625f;
  float d = v - mean;
  float vs = d * d;
  #pragma unroll
  for (int mm = 1; mm < 64; mm <<= 1) vs += __shfl_xor(vs, mm, 64);
  float rstd = rsqrtf(vs * 0.015625f + 1e-5f);
  float y = d * rstd * load1<F32>(w, lane) + load1<F32>(b, lane);
  out[(size_t)row * 64 + lane] = f2bf(y);
}

// ---------------- flash attention, fused Q-LN, no-max softmax, S^T trick ----
template<bool F32>
__global__ __launch_bounds__(256) void flash_kernel(
    const void* __restrict__ xq,     // (B*H*S, 64) raw
    const void* __restrict__ qnw, const void* __restrict__ qnb,
    const short* __restrict__ kp,    // (B*N, 64) bf16 pre-LN'd (ws)
    const void* __restrict__ vp,     // (B*N, 64) raw
    short* __restrict__ aout,        // bf16 scratch region inside d_out
    const int* __restrict__ flag) {
  if ((*flag != 0) == F32) return;
  __shared__ __align__(16) char ldsQ[256 * 144];
  __shared__ __align__(16) char ldsK[32 * 144];
  __shared__ __align__(16) char ldsV[64 * 72];

  int wg = blockIdx.x;
  int sblk = wg & 7;
  int bh = wg >> 3;
  int b = bh >> 4;
  int t = threadIdx.x;
  int wave = t >> 6, lane = t & 63;
  int m = lane & 15, q = lane >> 4;
  const float QSCALE = 0.125f * 1.4426950408889634f;  // scale * log2(e)

  // fused Q layernorm: thread t owns Q row (bh*S + sblk*256 + t)
  {
    size_t qbase = ((size_t)(bh * S_ + sblk * 256 + t)) * 64;
    s8v raw[8];
    float s = 0.f, ss = 0.f;
    #pragma unroll
    for (int i = 0; i < 8; i++) {
      raw[i] = load8bf<F32>(xq, qbase + i * 8);
      #pragma unroll
      for (int e = 0; e < 8; e++) { float f = bf2f(raw[i][e]); s += f; ss += f * f; }
    }
    float mean = s * 0.015625f;
    float var = ss * 0.015625f - mean * mean;
    float rstd = rsqrtf(var + 1e-5f);
    #pragma unroll
    for (int i = 0; i < 8; i++) {
      union { s8v v; unsigned u[4]; } o8;
      #pragma unroll
      for (int e = 0; e < 4; e++) {
        float f0 = ((bf2f(raw[i][2 * e])     - mean) * rstd * load1<F32>(qnw, i * 8 + 2 * e)
                    + load1<F32>(qnb, i * 8 + 2 * e)) * QSCALE;
        float f1 = ((bf2f(raw[i][2 * e + 1]) - mean) * rstd * load1<F32>(qnw, i * 8 + 2 * e + 1)
                    + load1<F32>(qnb, i * 8 + 2 * e + 1)) * QSCALE;
        o8.u[e] = pack2bf(f0, f1);
      }
      *(s8v*)(ldsQ + t * 144 + i * 16) = o8.v;
    }
  }
  __syncthreads();

  // Q B-frags: B[k=d=q*8+j][n=m], 4 m-tiles of 16 rows
  s8v qlo[4], qhi[4];
  #pragma unroll
  for (int mt = 0; mt < 4; mt++) {
    const char* qrow = ldsQ + (wave * 64 + mt * 16 + m) * 144;
    qlo[mt] = *(const s8v*)(qrow + q * 16);
    qhi[mt] = *(const s8v*)(qrow + 64 + q * 16);
  }

  f4v zero4 = {0.f, 0.f, 0.f, 0.f};
  f4v o[4][4];
  #pragma unroll
  for (int mt = 0; mt < 4; mt++)
    #pragma unroll
    for (int tt = 0; tt < 4; tt++) o[mt][tt] = zero4;
  float lsum[4] = {0.f, 0.f, 0.f, 0.f};

  const short* kb = kp + (size_t)b * N_ * 64;
  size_t vbase = (size_t)b * N_ * 64;
  int srow = t >> 3, t8 = t & 7;

  for (int c0 = 0; c0 < N_; c0 += 32) {
    __syncthreads();
    s8v kk = *(const s8v*)(kb + (size_t)(c0 + srow) * 64 + t8 * 8);
    s8v vv = load8bf<F32>(vp, vbase + (size_t)(c0 + srow) * 64 + t8 * 8);
    *(s8v*)(ldsK + srow * 144 + t8 * 16) = kk;
    #pragma unroll
    for (int j = 0; j < 8; j++)
      *(short*)(ldsV + (t8 * 8 + j) * 72 + srow * 2) = vv[j];
    __syncthreads();

    s8v a0lo = *(const s8v*)(ldsK + m * 144 + q * 16);
    s8v a0hi = *(const s8v*)(ldsK + m * 144 + 64 + q * 16);
    s8v a1lo = *(const s8v*)(ldsK + (16 + m) * 144 + q * 16);
    s8v a1hi = *(const s8v*)(ldsK + (16 + m) * 144 + 64 + q * 16);

    s8v vfrag[4];
    #pragma unroll
    for (int tt = 0; tt < 4; tt++) {
      s4v vl = *(const s4v*)(ldsV + (tt * 16 + m) * 72 + q * 8);
      s4v vh = *(const s4v*)(ldsV + (tt * 16 + m) * 72 + 32 + q * 8);
      s8v vf;
      #pragma unroll
      for (int j = 0; j < 4; j++) { vf[j] = vl[j]; vf[4 + j] = vh[j]; }
      vfrag[tt] = vf;
    }

    #pragma unroll
    for (int mt = 0; mt < 4; mt++) {
      f4v s0 = zero4, s1 = zero4;
      s0 = __builtin_amdgcn_mfma_f32_16x16x32_bf16(a0lo, qlo[mt], s0, 0, 0, 0);
      s0 = __builtin_amdgcn_mfma_f32_16x16x32_bf16(a0hi, qhi[mt], s0, 0, 0, 0);
      s1 = __builtin_amdgcn_mfma_f32_16x16x32_bf16(a1lo, qlo[mt], s1, 0, 0, 0);
      s1 = __builtin_amdgcn_mfma_f32_16x16x32_bf16(a1hi, qhi[mt], s1, 0, 0, 0);
      float p[8];
      #pragma unroll
      for (int i = 0; i < 4; i++) {
        p[i]     = __builtin_amdgcn_exp2f(fminf(s0[i], 64.0f));
        p[4 + i] = __builtin_amdgcn_exp2f(fminf(s1[i], 64.0f));
      }
      lsum[mt] += ((p[0] + p[1]) + (p[2] + p[3])) + ((p[4] + p[5]) + (p[6] + p[7]));
      union { s8v v; unsigned u[4]; } pa;
      #pragma unroll
      for (int i = 0; i < 4; i++) pa.u[i] = pack2bf(p[2 * i], p[2 * i + 1]);
      #pragma unroll
      for (int tt = 0; tt < 4; tt++)
        o[mt][tt] = __builtin_amdgcn_mfma_f32_16x16x32_bf16(pa.v, vfrag[tt], o[mt][tt], 0, 0, 0);
    }
  }

  #pragma unroll
  for (int mt = 0; mt < 4; mt++) {
    float l = lsum[mt];
    l += __shfl_xor(l, 16, 64);
    l += __shfl_xor(l, 32, 64);
    float inv = 1.0f / l;
    #pragma unroll
    for (int i = 0; i < 4; i++) {
      float invi = __shfl(inv, q * 4 + i, 64);
      int s = sblk * 256 + wave * 64 + mt * 16 + q * 4 + i;
      size_t orow = ((size_t)b * S_ + s) * D_ + (size_t)(bh & 15) * 64;
      #pragma unroll
      for (int tt = 0; tt < 4; tt++)
        aout[orow + tt * 16 + m] = f2bf(o[mt][tt][i] * invi);
    }
  }
}

// ---------------- LN over D=1024 (x always bf16; params raw dtype) --------
template<bool F32>
__global__ __launch_bounds__(256) void ln_d_kernel(
    const short* __restrict__ x, const void* __restrict__ w,
    const void* __restrict__ bb, short* __restrict__ y,
    const int* __restrict__ flag) {
  if ((*flag != 0) == F32) return;
  __shared__ float red[8];
  int row = blockIdx.x, t = threadIdx.x;
  int wave = t >> 6, lane = t & 63;
  const short* xr = x + (size_t)row * D_;
  s4v xv = *(const s4v*)(xr + t * 4);
  float f0 = bf2f(xv[0]), f1 = bf2f(xv[1]), f2 = bf2f(xv[2]), f3 = bf2f(xv[3]);
  float s = (f0 + f1) + (f2 + f3);
  float ss = (f0 * f0 + f1 * f1) + (f2 * f2 + f3 * f3);
  #pragma unroll
  for (int mm = 1; mm < 64; mm <<= 1) {
    s += __shfl_xor(s, mm, 64);
    ss += __shfl_xor(ss, mm, 64);
  }
  if (lane == 0) { red[wave] = s; red[4 + wave] = ss; }
  __syncthreads();
  s = (red[0] + red[1]) + (red[2] + red[3]);
  ss = (red[4] + red[5]) + (red[6] + red[7]);
  float mean = s * (1.0f / 1024.0f);
  float var = ss * (1.0f / 1024.0f) - mean * mean;
  float rstd = rsqrtf(var + 1e-5f);
  float fs[4] = {f0, f1, f2, f3};
  s4v yv;
  #pragma unroll
  for (int e = 0; e < 4; e++)
    yv[e] = f2bf((fs[e] - mean) * rstd * load1<F32>(w, t * 4 + e) + load1<F32>(bb, t * 4 + e));
  *(s4v*)(y + (size_t)row * D_ + t * 4) = yv;
}

// ---------------- projection GEMM: C(8192x1024) = Y * W^T ----------------
template<bool F32>
__global__ __launch_bounds__(256) void proj_gemm(
    const short* __restrict__ A, const void* __restrict__ Bw,
    void* __restrict__ C, const int* __restrict__ flag) {
  if ((*flag != 0) == F32) return;
  __shared__ __align__(16) char la[128 * 80];
  __shared__ __align__(16) char lb[128 * 80];
  int bm = (blockIdx.x >> 3) * 128;
  int bn = (blockIdx.x & 7) * 128;
  int wave = threadIdx.x >> 6, lane = threadIdx.x & 63;
  int m = lane & 15, q = lane >> 4;
  int wm = (wave & 1) * 64, wn = (wave >> 1) * 64;
  f4v zero4 = {0.f, 0.f, 0.f, 0.f};
  f4v acc[4][4];
  #pragma unroll
  for (int i = 0; i < 4; i++)
    #pragma unroll
    for (int j = 0; j < 4; j++) acc[i][j] = zero4;
  int sr = threadIdx.x >> 1, sh = (threadIdx.x & 1) * 16;
  for (int k0 = 0; k0 < 1024; k0 += 32) {
    __syncthreads();
    s8v a0 = *(const s8v*)(A + (size_t)(bm + sr) * 1024 + k0 + sh);
    s8v a1 = *(const s8v*)(A + (size_t)(bm + sr) * 1024 + k0 + sh + 8);
    s8v b0 = load8bf<F32>(Bw, (size_t)(bn + sr) * 1024 + k0 + sh);
    s8v b1 = load8bf<F32>(Bw, (size_t)(bn + sr) * 1024 + k0 + sh + 8);
    *(s8v*)(la + sr * 80 + sh * 2) = a0;
    *(s8v*)(la + sr * 80 + sh * 2 + 16) = a1;
    *(s8v*)(lb + sr * 80 + sh * 2) = b0;
    *(s8v*)(lb + sr * 80 + sh * 2 + 16) = b1;
    __syncthreads();
    s8v af[4], bfv[4];
    #pragma unroll
    for (int i = 0; i < 4; i++) af[i] = *(const s8v*)(la + (wm + i * 16 + m) * 80 + q * 16);
    #pragma unroll
    for (int j = 0; j < 4; j++) bfv[j] = *(const s8v*)(lb + (wn + j * 16 + m) * 80 + q * 16);
    #pragma unroll
    for (int i = 0; i < 4; i++)
      #pragma unroll
      for (int j = 0; j < 4; j++)
        acc[i][j] = __builtin_amdgcn_mfma_f32_16x16x32_bf16(af[i], bfv[j], acc[i][j], 0, 0, 0);
  }
  #pragma unroll
  for (int i = 0; i < 4; i++)
    #pragma unroll
    for (int j = 0; j < 4; j++)
      #pragma unroll
      for (int r = 0; r < 4; r++) {
        int row = bm + wm + i * 16 + q * 4 + r;
        int col = bn + wn + j * 16 + m;
        float val = acc[i][j][r];
        if constexpr (F32) ((float*)C)[(size_t)row * 1024 + col] = val;
        else ((short*)C)[(size_t)row * 1024 + col] = f2bf(val);
      }
}

extern "C" void kernel_launch(void* const* d_in, const int* in_sizes, int n_in,
                              void* d_out, int out_size, void* d_ws, size_t ws_size,
                              hipStream_t stream) {
  const void* xq  = d_in[0];
  const void* xk  = d_in[1];
  const void* xv  = d_in[2];
  const void* qnw = d_in[3];
  const void* qnb = d_in[4];
  const void* knw = d_in[5];
  const void* knb = d_in[6];
  const void* nw  = d_in[7];
  const void* nb  = d_in[8];
  const void* pw  = d_in[9];

  // ws layout: flag [0,64) | y bf16 [64, 64+16.78M) | k' bf16 [+1MB)
  int* flag  = (int*)d_ws;
  short* yws = (short*)((char*)d_ws + 64);
  short* kws = (short*)((char*)d_ws + 16777280);
  // attention output (always bf16) uses the front of d_out as scratch;
  // proj_gemm fully overwrites d_out afterwards and never reads it.
  short* aout = (short*)d_out;

  detect_dtype<<<1, 64, 0, stream>>>((const unsigned*)xq, flag);

  rownorm64<false><<<2048, 256, 0, stream>>>(xk, knw, knb, kws, B_ * N_, flag);
  rownorm64<true ><<<2048, 256, 0, stream>>>(xk, knw, knb, kws, B_ * N_, flag);

  flash_kernel<false><<<512, 256, 0, stream>>>(xq, qnw, qnb, kws, xv, aout, flag);
  flash_kernel<true ><<<512, 256, 0, stream>>>(xq, qnw, qnb, kws, xv, aout, flag);

  ln_d_kernel<false><<<B_ * S_, 256, 0, stream>>>(aout, nw, nb, yws, flag);
  ln_d_kernel<true ><<<B_ * S_, 256, 0, stream>>>(aout, nw, nb, yws, flag);

  proj_gemm<false><<<512, 256, 0, stream>>>(yws, pw, d_out, flag);
  proj_gemm<true ><<<512, 256, 0, stream>>>(yws, pw, d_out, flag);
}

// Round 8
// 232.395 us; speedup vs baseline: 1.1783x; 1.1783x over previous
//
#include <hip/hip_runtime.h>

#define B_ 4
#define S_ 2048
#define N_ 2048
#define H_ 16
#define D_ 1024

typedef short s4v __attribute__((ext_vector_type(4)));
typedef short s8v __attribute__((ext_vector_type(8)));
typedef float f4v __attribute__((ext_vector_type(4)));

__device__ __forceinline__ float bf2f(short s) {
  unsigned u = ((unsigned)(unsigned short)s) << 16;
  float f; __builtin_memcpy(&f, &u, 4); return f;
}
__device__ __forceinline__ short f2bf(float f) {
  unsigned u; __builtin_memcpy(&u, &f, 4);
  u += 0x7fffu + ((u >> 16) & 1u);
  return (short)(u >> 16);
}
__device__ __forceinline__ unsigned pack2bf(float a, float b) {
  unsigned ua, ub;
  __builtin_memcpy(&ua, &a, 4);
  __builtin_memcpy(&ub, &b, 4);
  return __builtin_amdgcn_perm(ub + 0x8000u, ua + 0x8000u, 0x07060302u);
}
// truncating pack (P values; bias cancels in softmax ratio num/denom)
__device__ __forceinline__ unsigned pk2(float a, float b) {
  unsigned ua, ub;
  __builtin_memcpy(&ua, &a, 4);
  __builtin_memcpy(&ub, &b, 4);
  return __builtin_amdgcn_perm(ub, ua, 0x07060302u);
}
__device__ __forceinline__ s8v load8f32(const float* p) {
  const f4v* q = (const f4v*)p;
  f4v a = q[0], b = q[1];
  union { s8v v; unsigned u[4]; } o;
  o.u[0] = pack2bf(a[0], a[1]); o.u[1] = pack2bf(a[2], a[3]);
  o.u[2] = pack2bf(b[0], b[1]); o.u[3] = pack2bf(b[2], b[3]);
  return o.v;
}

// ===== prep: K-LN (padded 144-B rows) + V transpose/permute =================
// blocks [0,2048): K-norm -> kws, row stride 72 shorts.
// blocks [2048,2112): VTP[b][nb32][d(64)][q(4)][slot(8)]: 4096-B linear blocks
// matching the PV B-frag order (slot j<4: key q*4+j ; j>=4: key 16+q*4+j-4).
__global__ __launch_bounds__(256) void prep_kernel(
    const float* __restrict__ xk, const float* __restrict__ knw,
    const float* __restrict__ knb, short* __restrict__ kws,
    const float* __restrict__ xv, short* __restrict__ vtp) {
  __shared__ __align__(16) short vstage[4][2048];
  int blk = blockIdx.x;
  if (blk < 2048) {
    int gid = blk * 256 + threadIdx.x;
    int row = gid >> 6, lane = gid & 63;
    float v = xk[(size_t)row * 64 + lane];
    float s = v;
    #pragma unroll
    for (int mm = 1; mm < 64; mm <<= 1) s += __shfl_xor(s, mm, 64);
    float mean = s * 0.015625f;
    float d = v - mean;
    float vs = d * d;
    #pragma unroll
    for (int mm = 1; mm < 64; mm <<= 1) vs += __shfl_xor(vs, mm, 64);
    float rstd = rsqrtf(vs * 0.015625f + 1e-5f);
    kws[(size_t)row * 72 + lane] = f2bf(d * rstd * knw[lane] + knb[lane]);
  } else {
    int wave = threadIdx.x >> 6, lane = threadIdx.x & 63;
    int u = (blk - 2048) * 4 + wave;        // (b,nb) unit, 0..255
    int b = u >> 6, nb = u & 63;
    int r = lane >> 1, dh = lane & 1;       // V row within 32-block, d-half
    const float* src = xv + ((size_t)(b * N_ + nb * 32 + r)) * 64 + dh * 32;
    int qq = (r & 15) >> 2;
    int slot = ((r >> 4) << 2) + (r & 3);
    short* wbase = &vstage[wave][0];
    #pragma unroll
    for (int jj = 0; jj < 32; jj += 4) {
      f4v f = *(const f4v*)(src + jj);
      #pragma unroll
      for (int e = 0; e < 4; e++) {
        int d = dh * 32 + jj + e;
        wbase[d * 32 + qq * 8 + slot] = f2bf(f[e]);
      }
    }
    __syncthreads();
    s8v* dst = (s8v*)(vtp + (size_t)u * 2048 + lane * 32);
    const s8v* sp = (const s8v*)(wbase + lane * 32);
    dst[0] = sp[0]; dst[1] = sp[1]; dst[2] = sp[2]; dst[3] = sp[3];
  }
}

// ===== flash: fused Q-LN, S^T trick, MFMA denominators, 64-key chunks =======
__global__ __launch_bounds__(256) void flash_kernel(
    const float* __restrict__ xq, const float* __restrict__ qnw,
    const float* __restrict__ qnb, const short* __restrict__ kws,
    const short* __restrict__ vtp, short* __restrict__ aout) {
  __shared__ union {
    char qs[256 * 144];
    struct { char k[9216]; char v[8192]; } kv;
  } lds;
  int blk = blockIdx.x;
  int sblk = blk & 7, bh = blk >> 3, b = bh >> 4;
  int t = threadIdx.x, wave = t >> 6, lane = t & 63;
  int m = lane & 15, q = lane >> 4;
  const float QSCALE = 0.125f * 1.4426950408889634f;  // scale * log2(e)

  // fused Q layernorm, thread t owns one q-row
  {
    const float* qr = xq + ((size_t)bh * S_ + sblk * 256 + t) * 64;
    float s = 0.f, ss = 0.f;
    #pragma unroll
    for (int i = 0; i < 16; i++) {
      f4v f = *(const f4v*)(qr + i * 4);
      s += (f[0] + f[1]) + (f[2] + f[3]);
      ss += (f[0] * f[0] + f[1] * f[1]) + (f[2] * f[2] + f[3] * f[3]);
    }
    float mean = s * 0.015625f;
    float rstd = rsqrtf(ss * 0.015625f - mean * mean + 1e-5f);
    #pragma unroll
    for (int i = 0; i < 8; i++) {
      f4v fa = *(const f4v*)(qr + i * 8);
      f4v fb = *(const f4v*)(qr + i * 8 + 4);
      float y[8];
      #pragma unroll
      for (int e = 0; e < 4; e++) {
        y[e]     = ((fa[e] - mean) * rstd * qnw[i * 8 + e]     + qnb[i * 8 + e])     * QSCALE;
        y[4 + e] = ((fb[e] - mean) * rstd * qnw[i * 8 + 4 + e] + qnb[i * 8 + 4 + e]) * QSCALE;
      }
      union { s8v v; unsigned u[4]; } o8;
      #pragma unroll
      for (int e = 0; e < 4; e++) o8.u[e] = pack2bf(y[2 * e], y[2 * e + 1]);
      *(s8v*)(lds.qs + t * 144 + i * 16) = o8.v;
    }
  }
  __syncthreads();

  s8v qlo[4], qhi[4];
  #pragma unroll
  for (int mt = 0; mt < 4; mt++) {
    const char* qrow = lds.qs + (wave * 64 + mt * 16 + m) * 144;
    qlo[mt] = *(const s8v*)(qrow + q * 16);
    qhi[mt] = *(const s8v*)(qrow + 64 + q * 16);
  }

  f4v zero4 = {0.f, 0.f, 0.f, 0.f};
  f4v o[4][4], lacc[4];
  #pragma unroll
  for (int mt = 0; mt < 4; mt++) {
    lacc[mt] = zero4;
    #pragma unroll
    for (int tt = 0; tt < 4; tt++) o[mt][tt] = zero4;
  }
  s8v ones;
  #pragma unroll
  for (int e = 0; e < 8; e++) ones[e] = (short)0x3F80;  // bf16 1.0

  const char* kb = (const char*)kws + (size_t)b * N_ * 144;
  const char* vb = (const char*)vtp + (size_t)b * 64 * 4096;

  for (int c0 = 0; c0 < N_; c0 += 64) {
    const char* kg = kb + (size_t)c0 * 144;           // 9216 B linear
    const char* vg = vb + (size_t)(c0 >> 5) * 4096;   // 8192 B linear
    s8v k0 = *(const s8v*)(kg + t * 16);
    s8v k1 = *(const s8v*)(kg + 4096 + t * 16);
    s8v k2 = {};
    if (t < 64) k2 = *(const s8v*)(kg + 8192 + t * 16);
    s8v v0 = *(const s8v*)(vg + t * 16);
    s8v v1 = *(const s8v*)(vg + 4096 + t * 16);
    __syncthreads();
    *(s8v*)(lds.kv.k + t * 16) = k0;
    *(s8v*)(lds.kv.k + 4096 + t * 16) = k1;
    if (t < 64) *(s8v*)(lds.kv.k + 8192 + t * 16) = k2;
    *(s8v*)(lds.kv.v + t * 16) = v0;
    *(s8v*)(lds.kv.v + 4096 + t * 16) = v1;
    __syncthreads();

    #pragma unroll
    for (int g = 0; g < 2; g++) {
      s8v a0lo = *(const s8v*)(lds.kv.k + (g * 32 + m) * 144 + q * 16);
      s8v a0hi = *(const s8v*)(lds.kv.k + (g * 32 + m) * 144 + 64 + q * 16);
      s8v a1lo = *(const s8v*)(lds.kv.k + (g * 32 + 16 + m) * 144 + q * 16);
      s8v a1hi = *(const s8v*)(lds.kv.k + (g * 32 + 16 + m) * 144 + 64 + q * 16);
      s8v vf[4];
      #pragma unroll
      for (int tt = 0; tt < 4; tt++)
        vf[tt] = *(const s8v*)(lds.kv.v + g * 4096 + (tt * 16 + m) * 64 + q * 16);

      #pragma unroll
      for (int mt = 0; mt < 4; mt++) {
        f4v s0 = zero4, s1 = zero4;
        s0 = __builtin_amdgcn_mfma_f32_16x16x32_bf16(a0lo, qlo[mt], s0, 0, 0, 0);
        s0 = __builtin_amdgcn_mfma_f32_16x16x32_bf16(a0hi, qhi[mt], s0, 0, 0, 0);
        s1 = __builtin_amdgcn_mfma_f32_16x16x32_bf16(a1lo, qlo[mt], s1, 0, 0, 0);
        s1 = __builtin_amdgcn_mfma_f32_16x16x32_bf16(a1hi, qhi[mt], s1, 0, 0, 0);
        float p[8];
        #pragma unroll
        for (int i = 0; i < 4; i++) {
          p[i]     = __builtin_amdgcn_exp2f(fminf(s0[i], 64.0f));
          p[4 + i] = __builtin_amdgcn_exp2f(fminf(s1[i], 64.0f));
        }
        union { s8v v; unsigned u[4]; } pa;
        #pragma unroll
        for (int i = 0; i < 4; i++) pa.u[i] = pk2(p[2 * i], p[2 * i + 1]);
        lacc[mt] = __builtin_amdgcn_mfma_f32_16x16x32_bf16(pa.v, ones, lacc[mt], 0, 0, 0);
        #pragma unroll
        for (int tt = 0; tt < 4; tt++)
          o[mt][tt] = __builtin_amdgcn_mfma_f32_16x16x32_bf16(pa.v, vf[tt], o[mt][tt], 0, 0, 0);
      }
    }
  }

  #pragma unroll
  for (int mt = 0; mt < 4; mt++) {
    #pragma unroll
    for (int i = 0; i < 4; i++) {
      float inv = __builtin_amdgcn_rcpf(lacc[mt][i]);
      int srow = sblk * 256 + wave * 64 + mt * 16 + q * 4 + i;
      size_t orow = ((size_t)b * S_ + srow) * D_ + (size_t)(bh & 15) * 64;
      #pragma unroll
      for (int tt = 0; tt < 4; tt++)
        aout[orow + tt * 16 + m] = f2bf(o[mt][tt][i] * inv);
    }
  }
}

// ===== LN over D=1024, row-major output ====================================
__global__ __launch_bounds__(256) void ln_d_kernel(
    const short* __restrict__ x, const float* __restrict__ w,
    const float* __restrict__ bb, short* __restrict__ y) {
  __shared__ float red[8];
  int row = blockIdx.x, t = threadIdx.x;
  int wave = t >> 6, lane = t & 63;
  const short* xr = x + (size_t)row * D_;
  s4v xv = *(const s4v*)(xr + t * 4);
  float f0 = bf2f(xv[0]), f1 = bf2f(xv[1]), f2 = bf2f(xv[2]), f3 = bf2f(xv[3]);
  float s = (f0 + f1) + (f2 + f3);
  float ss = (f0 * f0 + f1 * f1) + (f2 * f2 + f3 * f3);
  #pragma unroll
  for (int mm = 1; mm < 64; mm <<= 1) {
    s += __shfl_xor(s, mm, 64);
    ss += __shfl_xor(ss, mm, 64);
  }
  if (lane == 0) { red[wave] = s; red[4 + wave] = ss; }
  __syncthreads();
  s = (red[0] + red[1]) + (red[2] + red[3]);
  ss = (red[4] + red[5]) + (red[6] + red[7]);
  float mean = s * (1.0f / 1024.0f);
  float rstd = rsqrtf(ss * (1.0f / 1024.0f) - mean * mean + 1e-5f);
  float fs[4] = {f0, f1, f2, f3};
  s4v yv;
  #pragma unroll
  for (int e = 0; e < 4; e++)
    yv[e] = f2bf((fs[e] - mean) * rstd * w[t * 4 + e] + bb[t * 4 + e]);
  *(s4v*)(y + (size_t)row * D_ + t * 4) = yv;
}

// ===== proj GEMM: C(8192x1024) = Y * W^T, OUTPUT = FLOAT32 =================
__global__ __launch_bounds__(256) void proj_gemm(
    const short* __restrict__ A, const float* __restrict__ Bw,
    float* __restrict__ C) {
  __shared__ __align__(16) char la[128 * 80];
  __shared__ __align__(16) char lb[128 * 80];
  int bm = (blockIdx.x >> 3) * 128;
  int bn = (blockIdx.x & 7) * 128;
  int wave = threadIdx.x >> 6, lane = threadIdx.x & 63;
  int m = lane & 15, q = lane >> 4;
  int wm = (wave & 1) * 64, wn = (wave >> 1) * 64;
  f4v zero4 = {0.f, 0.f, 0.f, 0.f};
  f4v acc[4][4];
  #pragma unroll
  for (int i = 0; i < 4; i++)
    #pragma unroll
    for (int j = 0; j < 4; j++) acc[i][j] = zero4;
  int sr = threadIdx.x >> 1, sh = (threadIdx.x & 1) * 16;
  for (int k0 = 0; k0 < 1024; k0 += 32) {
    __syncthreads();
    s8v a0 = *(const s8v*)(A + (size_t)(bm + sr) * 1024 + k0 + sh);
    s8v a1 = *(const s8v*)(A + (size_t)(bm + sr) * 1024 + k0 + sh + 8);
    s8v b0 = load8f32(Bw + (size_t)(bn + sr) * 1024 + k0 + sh);
    s8v b1 = load8f32(Bw + (size_t)(bn + sr) * 1024 + k0 + sh + 8);
    *(s8v*)(la + sr * 80 + sh * 2) = a0;
    *(s8v*)(la + sr * 80 + sh * 2 + 16) = a1;
    *(s8v*)(lb + sr * 80 + sh * 2) = b0;
    *(s8v*)(lb + sr * 80 + sh * 2 + 16) = b1;
    __syncthreads();
    s8v af[4], bfv[4];
    #pragma unroll
    for (int i = 0; i < 4; i++) af[i] = *(const s8v*)(la + (wm + i * 16 + m) * 80 + q * 16);
    #pragma unroll
    for (int j = 0; j < 4; j++) bfv[j] = *(const s8v*)(lb + (wn + j * 16 + m) * 80 + q * 16);
    #pragma unroll
    for (int i = 0; i < 4; i++)
      #pragma unroll
      for (int j = 0; j < 4; j++)
        acc[i][j] = __builtin_amdgcn_mfma_f32_16x16x32_bf16(af[i], bfv[j], acc[i][j], 0, 0, 0);
  }
  #pragma unroll
  for (int i = 0; i < 4; i++)
    #pragma unroll
    for (int j = 0; j < 4; j++)
      #pragma unroll
      for (int r = 0; r < 4; r++) {
        int row = bm + wm + i * 16 + q * 4 + r;
        int col = bn + wn + j * 16 + m;
        C[(size_t)row * 1024 + col] = acc[i][j][r];   // f32 out (ref dtype!)
      }
}

extern "C" void kernel_launch(void* const* d_in, const int* in_sizes, int n_in,
                              void* d_out, int out_size, void* d_ws, size_t ws_size,
                              hipStream_t stream) {
  const float* xq  = (const float*)d_in[0];
  const float* xk  = (const float*)d_in[1];
  const float* xv  = (const float*)d_in[2];
  const float* qnw = (const float*)d_in[3];
  const float* qnb = (const float*)d_in[4];
  const float* knw = (const float*)d_in[5];
  const float* knb = (const float*)d_in[6];
  const float* nw  = (const float*)d_in[7];
  const float* nb  = (const float*)d_in[8];
  const float* pw  = (const float*)d_in[9];
  float* out = (float*)d_out;

  // ws: kws [0,0x120000) padded K; VTP [0x120000,0x220000); both dead after
  // flash, then y (row-major bf16) reuses [0, 16.78 MB).
  short* kws = (short*)d_ws;
  short* vtp = (short*)((char*)d_ws + 0x120000);
  short* yws = (short*)d_ws;
  // flash writes bf16 scratch into the front of d_out (33.5 MB as f32);
  // proj fully overwrites d_out in f32 and never reads it.
  short* aout = (short*)d_out;

  prep_kernel<<<2112, 256, 0, stream>>>(xk, knw, knb, kws, xv, vtp);
  flash_kernel<<<512, 256, 0, stream>>>(xq, qnw, qnb, kws, vtp, aout);
  ln_d_kernel<<<B_ * S_, 256, 0, stream>>>(aout, nw, nb, yws);
  proj_gemm<<<512, 256, 0, stream>>>(yws, pw, out);
}

// Round 9
// 230.129 us; speedup vs baseline: 1.1899x; 1.0098x over previous
//
#include <hip/hip_runtime.h>

#define B_ 4
#define S_ 2048
#define N_ 2048
#define H_ 16
#define D_ 1024

typedef short s4v __attribute__((ext_vector_type(4)));
typedef short s8v __attribute__((ext_vector_type(8)));
typedef float f4v __attribute__((ext_vector_type(4)));

__device__ __forceinline__ float bf2f(short s) {
  unsigned u = ((unsigned)(unsigned short)s) << 16;
  float f; __builtin_memcpy(&f, &u, 4); return f;
}
__device__ __forceinline__ short f2bf(float f) {
  unsigned u; __builtin_memcpy(&u, &f, 4);
  u += 0x7fffu + ((u >> 16) & 1u);
  return (short)(u >> 16);
}
__device__ __forceinline__ unsigned pack2bf(float a, float b) {
  unsigned ua, ub;
  __builtin_memcpy(&ua, &a, 4);
  __builtin_memcpy(&ub, &b, 4);
  return __builtin_amdgcn_perm(ub + 0x8000u, ua + 0x8000u, 0x07060302u);
}
// truncating pack (P values; bias cancels in softmax ratio num/denom)
__device__ __forceinline__ unsigned pk2(float a, float b) {
  unsigned ua, ub;
  __builtin_memcpy(&ua, &a, 4);
  __builtin_memcpy(&ub, &b, 4);
  return __builtin_amdgcn_perm(ub, ua, 0x07060302u);
}
__device__ __forceinline__ s8v load8f32(const float* p) {
  const f4v* q = (const f4v*)p;
  f4v a = q[0], b = q[1];
  union { s8v v; unsigned u[4]; } o;
  o.u[0] = pack2bf(a[0], a[1]); o.u[1] = pack2bf(a[2], a[3]);
  o.u[2] = pack2bf(b[0], b[1]); o.u[3] = pack2bf(b[2], b[3]);
  return o.v;
}

// ===== prep: K-LN (padded 144-B rows) + V transpose/permute =================
__global__ __launch_bounds__(256) void prep_kernel(
    const float* __restrict__ xk, const float* __restrict__ knw,
    const float* __restrict__ knb, short* __restrict__ kws,
    const float* __restrict__ xv, short* __restrict__ vtp) {
  __shared__ __align__(16) short vstage[4][2048];
  int blk = blockIdx.x;
  if (blk < 2048) {
    int gid = blk * 256 + threadIdx.x;
    int row = gid >> 6, lane = gid & 63;
    float v = xk[(size_t)row * 64 + lane];
    float s = v;
    #pragma unroll
    for (int mm = 1; mm < 64; mm <<= 1) s += __shfl_xor(s, mm, 64);
    float mean = s * 0.015625f;
    float d = v - mean;
    float vs = d * d;
    #pragma unroll
    for (int mm = 1; mm < 64; mm <<= 1) vs += __shfl_xor(vs, mm, 64);
    float rstd = rsqrtf(vs * 0.015625f + 1e-5f);
    kws[(size_t)row * 72 + lane] = f2bf(d * rstd * knw[lane] + knb[lane]);
  } else {
    int wave = threadIdx.x >> 6, lane = threadIdx.x & 63;
    int u = (blk - 2048) * 4 + wave;        // (b,nb) unit, 0..255
    int b = u >> 6, nb = u & 63;
    int r = lane >> 1, dh = lane & 1;       // V row within 32-block, d-half
    const float* src = xv + ((size_t)(b * N_ + nb * 32 + r)) * 64 + dh * 32;
    int qq = (r & 15) >> 2;
    int slot = ((r >> 4) << 2) + (r & 3);
    short* wbase = &vstage[wave][0];
    #pragma unroll
    for (int jj = 0; jj < 32; jj += 4) {
      f4v f = *(const f4v*)(src + jj);
      #pragma unroll
      for (int e = 0; e < 4; e++) {
        int d = dh * 32 + jj + e;
        wbase[d * 32 + qq * 8 + slot] = f2bf(f[e]);
      }
    }
    __syncthreads();
    s8v* dst = (s8v*)(vtp + (size_t)u * 2048 + lane * 32);
    const s8v* sp = (const s8v*)(wbase + lane * 32);
    dst[0] = sp[0]; dst[1] = sp[1]; dst[2] = sp[2]; dst[3] = sp[3];
  }
}

// ===== flash v2: 128 q-rows/block (grid 1024, 4 blocks/CU), 2 m-tiles/wave ==
__global__ __launch_bounds__(256, 4) void flash_kernel(
    const float* __restrict__ xq, const float* __restrict__ qnw,
    const float* __restrict__ qnb, const short* __restrict__ kws,
    const short* __restrict__ vtp, short* __restrict__ aout) {
  __shared__ union {
    char qs[128 * 144];                       // 18432 B
    struct { char k[9216]; char v[8192]; } kv;
  } lds;
  int blk = blockIdx.x;
  int sblk = blk & 15, bh = blk >> 4, b = bh >> 4;
  int t = threadIdx.x, wave = t >> 6, lane = t & 63;
  int m = lane & 15, q = lane >> 4;
  const float QSCALE = 0.125f * 1.4426950408889634f;  // scale * log2(e)

  // fused Q layernorm: 2 threads per row (t=2r+half), pair-combine via shfl
  {
    int r = t >> 1, half = t & 1;
    const float* qr = xq + ((size_t)bh * S_ + sblk * 128 + r) * 64 + half * 32;
    f4v f[8];
    float s = 0.f, ss = 0.f;
    #pragma unroll
    for (int i = 0; i < 8; i++) {
      f[i] = *(const f4v*)(qr + i * 4);
      s += (f[i][0] + f[i][1]) + (f[i][2] + f[i][3]);
      ss += (f[i][0] * f[i][0] + f[i][1] * f[i][1]) + (f[i][2] * f[i][2] + f[i][3] * f[i][3]);
    }
    s += __shfl_xor(s, 1, 64);
    ss += __shfl_xor(ss, 1, 64);
    float mean = s * 0.015625f;
    float rstd = rsqrtf(ss * 0.015625f - mean * mean + 1e-5f);
    #pragma unroll
    for (int i = 0; i < 4; i++) {          // s8v i covers elems half*32+i*8..+8
      float y[8];
      #pragma unroll
      for (int e = 0; e < 4; e++) {
        int gi = half * 32 + i * 8;
        y[e]     = ((f[2 * i][e]     - mean) * rstd * qnw[gi + e]     + qnb[gi + e])     * QSCALE;
        y[4 + e] = ((f[2 * i + 1][e] - mean) * rstd * qnw[gi + 4 + e] + qnb[gi + 4 + e]) * QSCALE;
      }
      union { s8v v; unsigned u[4]; } o8;
      #pragma unroll
      for (int e = 0; e < 4; e++) o8.u[e] = pack2bf(y[2 * e], y[2 * e + 1]);
      *(s8v*)(lds.qs + r * 144 + half * 64 + i * 16) = o8.v;
    }
  }
  __syncthreads();

  // Q B-frags: wave owns rows [wave*32, wave*32+32), mt in {0,1}
  s8v qlo[2], qhi[2];
  #pragma unroll
  for (int mt = 0; mt < 2; mt++) {
    const char* qrow = lds.qs + (wave * 32 + mt * 16 + m) * 144;
    qlo[mt] = *(const s8v*)(qrow + q * 16);
    qhi[mt] = *(const s8v*)(qrow + 64 + q * 16);
  }

  f4v zero4 = {0.f, 0.f, 0.f, 0.f};
  f4v o[2][4], lacc[2];
  #pragma unroll
  for (int mt = 0; mt < 2; mt++) {
    lacc[mt] = zero4;
    #pragma unroll
    for (int tt = 0; tt < 4; tt++) o[mt][tt] = zero4;
  }
  s8v ones;
  #pragma unroll
  for (int e = 0; e < 8; e++) ones[e] = (short)0x3F80;  // bf16 1.0

  const char* kb = (const char*)kws + (size_t)b * N_ * 144;
  const char* vb = (const char*)vtp + (size_t)b * 64 * 4096;

  for (int c0 = 0; c0 < N_; c0 += 64) {
    const char* kg = kb + (size_t)c0 * 144;           // 9216 B linear
    const char* vg = vb + (size_t)(c0 >> 5) * 4096;   // 8192 B linear
    // issue global loads before the barrier (overlap w/ previous compute)
    s8v k0 = *(const s8v*)(kg + t * 16);
    s8v k1 = *(const s8v*)(kg + 4096 + t * 16);
    s8v k2 = {};
    if (t < 64) k2 = *(const s8v*)(kg + 8192 + t * 16);
    s8v v0 = *(const s8v*)(vg + t * 16);
    s8v v1 = *(const s8v*)(vg + 4096 + t * 16);
    __syncthreads();
    *(s8v*)(lds.kv.k + t * 16) = k0;
    *(s8v*)(lds.kv.k + 4096 + t * 16) = k1;
    if (t < 64) *(s8v*)(lds.kv.k + 8192 + t * 16) = k2;
    *(s8v*)(lds.kv.v + t * 16) = v0;
    *(s8v*)(lds.kv.v + 4096 + t * 16) = v1;
    __syncthreads();

    #pragma unroll
    for (int g = 0; g < 2; g++) {
      s8v a0lo = *(const s8v*)(lds.kv.k + (g * 32 + m) * 144 + q * 16);
      s8v a0hi = *(const s8v*)(lds.kv.k + (g * 32 + m) * 144 + 64 + q * 16);
      s8v a1lo = *(const s8v*)(lds.kv.k + (g * 32 + 16 + m) * 144 + q * 16);
      s8v a1hi = *(const s8v*)(lds.kv.k + (g * 32 + 16 + m) * 144 + 64 + q * 16);
      s8v vf[4];
      #pragma unroll
      for (int tt = 0; tt < 4; tt++)
        vf[tt] = *(const s8v*)(lds.kv.v + g * 4096 + (tt * 16 + m) * 64 + q * 16);

      #pragma unroll
      for (int mt = 0; mt < 2; mt++) {
        f4v s0 = zero4, s1 = zero4;
        s0 = __builtin_amdgcn_mfma_f32_16x16x32_bf16(a0lo, qlo[mt], s0, 0, 0, 0);
        s0 = __builtin_amdgcn_mfma_f32_16x16x32_bf16(a0hi, qhi[mt], s0, 0, 0, 0);
        s1 = __builtin_amdgcn_mfma_f32_16x16x32_bf16(a1lo, qlo[mt], s1, 0, 0, 0);
        s1 = __builtin_amdgcn_mfma_f32_16x16x32_bf16(a1hi, qhi[mt], s1, 0, 0, 0);
        float p[8];
        #pragma unroll
        for (int i = 0; i < 4; i++) {
          p[i]     = __builtin_amdgcn_exp2f(fminf(s0[i], 64.0f));
          p[4 + i] = __builtin_amdgcn_exp2f(fminf(s1[i], 64.0f));
        }
        union { s8v v; unsigned u[4]; } pa;
        #pragma unroll
        for (int i = 0; i < 4; i++) pa.u[i] = pk2(p[2 * i], p[2 * i + 1]);
        lacc[mt] = __builtin_amdgcn_mfma_f32_16x16x32_bf16(pa.v, ones, lacc[mt], 0, 0, 0);
        #pragma unroll
        for (int tt = 0; tt < 4; tt++)
          o[mt][tt] = __builtin_amdgcn_mfma_f32_16x16x32_bf16(pa.v, vf[tt], o[mt][tt], 0, 0, 0);
      }
    }
  }

  #pragma unroll
  for (int mt = 0; mt < 2; mt++) {
    #pragma unroll
    for (int i = 0; i < 4; i++) {
      float inv = __builtin_amdgcn_rcpf(lacc[mt][i]);
      int srow = sblk * 128 + wave * 32 + mt * 16 + q * 4 + i;
      size_t orow = ((size_t)b * S_ + srow) * D_ + (size_t)(bh & 15) * 64;
      #pragma unroll
      for (int tt = 0; tt < 4; tt++)
        aout[orow + tt * 16 + m] = f2bf(o[mt][tt][i] * inv);
    }
  }
}

// ===== LN over D=1024, row-major output ====================================
__global__ __launch_bounds__(256) void ln_d_kernel(
    const short* __restrict__ x, const float* __restrict__ w,
    const float* __restrict__ bb, short* __restrict__ y) {
  __shared__ float red[8];
  int row = blockIdx.x, t = threadIdx.x;
  int wave = t >> 6, lane = t & 63;
  const short* xr = x + (size_t)row * D_;
  s4v xv = *(const s4v*)(xr + t * 4);
  float f0 = bf2f(xv[0]), f1 = bf2f(xv[1]), f2 = bf2f(xv[2]), f3 = bf2f(xv[3]);
  float s = (f0 + f1) + (f2 + f3);
  float ss = (f0 * f0 + f1 * f1) + (f2 * f2 + f3 * f3);
  #pragma unroll
  for (int mm = 1; mm < 64; mm <<= 1) {
    s += __shfl_xor(s, mm, 64);
    ss += __shfl_xor(ss, mm, 64);
  }
  if (lane == 0) { red[wave] = s; red[4 + wave] = ss; }
  __syncthreads();
  s = (red[0] + red[1]) + (red[2] + red[3]);
  ss = (red[4] + red[5]) + (red[6] + red[7]);
  float mean = s * (1.0f / 1024.0f);
  float rstd = rsqrtf(ss * (1.0f / 1024.0f) - mean * mean + 1e-5f);
  float fs[4] = {f0, f1, f2, f3};
  s4v yv;
  #pragma unroll
  for (int e = 0; e < 4; e++)
    yv[e] = f2bf((fs[e] - mean) * rstd * w[t * 4 + e] + bb[t * 4 + e]);
  *(s4v*)(y + (size_t)row * D_ + t * 4) = yv;
}

// ===== proj GEMM: C = Y * W^T, f32 out; loads hoisted above barrier ========
__global__ __launch_bounds__(256) void proj_gemm(
    const short* __restrict__ A, const float* __restrict__ Bw,
    float* __restrict__ C) {
  __shared__ __align__(16) char la[128 * 80];
  __shared__ __align__(16) char lb[128 * 80];
  int bm = (blockIdx.x >> 3) * 128;
  int bn = (blockIdx.x & 7) * 128;
  int wave = threadIdx.x >> 6, lane = threadIdx.x & 63;
  int m = lane & 15, q = lane >> 4;
  int wm = (wave & 1) * 64, wn = (wave >> 1) * 64;
  f4v zero4 = {0.f, 0.f, 0.f, 0.f};
  f4v acc[4][4];
  #pragma unroll
  for (int i = 0; i < 4; i++)
    #pragma unroll
    for (int j = 0; j < 4; j++) acc[i][j] = zero4;
  int sr = threadIdx.x >> 1, sh = (threadIdx.x & 1) * 16;
  for (int k0 = 0; k0 < 1024; k0 += 32) {
    // global loads issued BEFORE the barrier: latency overlaps prev compute
    s8v a0 = *(const s8v*)(A + (size_t)(bm + sr) * 1024 + k0 + sh);
    s8v a1 = *(const s8v*)(A + (size_t)(bm + sr) * 1024 + k0 + sh + 8);
    s8v b0 = load8f32(Bw + (size_t)(bn + sr) * 1024 + k0 + sh);
    s8v b1 = load8f32(Bw + (size_t)(bn + sr) * 1024 + k0 + sh + 8);
    __syncthreads();
    *(s8v*)(la + sr * 80 + sh * 2) = a0;
    *(s8v*)(la + sr * 80 + sh * 2 + 16) = a1;
    *(s8v*)(lb + sr * 80 + sh * 2) = b0;
    *(s8v*)(lb + sr * 80 + sh * 2 + 16) = b1;
    __syncthreads();
    s8v af[4], bfv[4];
    #pragma unroll
    for (int i = 0; i < 4; i++) af[i] = *(const s8v*)(la + (wm + i * 16 + m) * 80 + q * 16);
    #pragma unroll
    for (int j = 0; j < 4; j++) bfv[j] = *(const s8v*)(lb + (wn + j * 16 + m) * 80 + q * 16);
    #pragma unroll
    for (int i = 0; i < 4; i++)
      #pragma unroll
      for (int j = 0; j < 4; j++)
        acc[i][j] = __builtin_amdgcn_mfma_f32_16x16x32_bf16(af[i], bfv[j], acc[i][j], 0, 0, 0);
  }
  #pragma unroll
  for (int i = 0; i < 4; i++)
    #pragma unroll
    for (int j = 0; j < 4; j++)
      #pragma unroll
      for (int r = 0; r < 4; r++) {
        int row = bm + wm + i * 16 + q * 4 + r;
        int col = bn + wn + j * 16 + m;
        C[(size_t)row * 1024 + col] = acc[i][j][r];   // f32 out (ref dtype)
      }
}

extern "C" void kernel_launch(void* const* d_in, const int* in_sizes, int n_in,
                              void* d_out, int out_size, void* d_ws, size_t ws_size,
                              hipStream_t stream) {
  const float* xq  = (const float*)d_in[0];
  const float* xk  = (const float*)d_in[1];
  const float* xv  = (const float*)d_in[2];
  const float* qnw = (const float*)d_in[3];
  const float* qnb = (const float*)d_in[4];
  const float* knw = (const float*)d_in[5];
  const float* knb = (const float*)d_in[6];
  const float* nw  = (const float*)d_in[7];
  const float* nb  = (const float*)d_in[8];
  const float* pw  = (const float*)d_in[9];
  float* out = (float*)d_out;

  // ws: kws [0,0x120000) padded K; VTP [0x120000,0x220000); both dead after
  // flash, then y (row-major bf16) reuses [0, 16.78 MB).
  short* kws = (short*)d_ws;
  short* vtp = (short*)((char*)d_ws + 0x120000);
  short* yws = (short*)d_ws;
  // flash writes bf16 scratch into the front half of d_out (f32 view);
  // proj fully overwrites d_out in f32 and never reads it.
  short* aout = (short*)d_out;

  prep_kernel<<<2112, 256, 0, stream>>>(xk, knw, knb, kws, xv, vtp);
  flash_kernel<<<1024, 256, 0, stream>>>(xq, qnw, qnb, kws, vtp, aout);
  ln_d_kernel<<<B_ * S_, 256, 0, stream>>>(aout, nw, nb, yws);
  proj_gemm<<<512, 256, 0, stream>>>(yws, pw, out);
}